// Round 1
// baseline (616.957 us; speedup 1.0000x reference)
//
#include <hip/hip_runtime.h>
#include <math.h>

// Problem constants (fixed by setup_inputs)
#define BB 128
#define HH 8
#define DD 256
#define MM 8192
#define BH (BB*HH)   // 1024
#define RANK 16

// ---------------------------------------------------------------------------
// K1: q[b,h,i] = sum_j (probe_r[h,i,j] + i probe_i[h,i,j]) * (pr[b,j] + i pi[b,j])
// block: (b-pair, h), 256 threads (one per i). psi staged in LDS.
// ---------------------------------------------------------------------------
__global__ __launch_bounds__(256) void k_q(
    const float* __restrict__ psi, const float* __restrict__ probe_r,
    const float* __restrict__ probe_i, float* __restrict__ qr, float* __restrict__ qi) {
  __shared__ float2 ps0[DD];
  __shared__ float2 ps1[DD];
  int b0 = blockIdx.x * 2;
  int h  = blockIdx.y;
  int i  = threadIdx.x;
  ps0[i] = ((const float2*)psi)[(size_t)b0 * DD + i];
  ps1[i] = ((const float2*)psi)[(size_t)(b0 + 1) * DD + i];
  __syncthreads();
  const float* rr = probe_r + ((size_t)h * DD + i) * DD;
  const float* ri = probe_i + ((size_t)h * DD + i) * DD;
  float a0r = 0.f, a0i = 0.f, a1r = 0.f, a1i = 0.f;
  for (int j = 0; j < DD; j += 4) {
    float4 xr = *(const float4*)(rr + j);
    float4 xi = *(const float4*)(ri + j);
    float2 p0 = ps0[j+0], p1 = ps0[j+1], p2 = ps0[j+2], p3 = ps0[j+3];
    a0r += xr.x*p0.x - xi.x*p0.y;  a0i += xr.x*p0.y + xi.x*p0.x;
    a0r += xr.y*p1.x - xi.y*p1.y;  a0i += xr.y*p1.y + xi.y*p1.x;
    a0r += xr.z*p2.x - xi.z*p2.y;  a0i += xr.z*p2.y + xi.z*p2.x;
    a0r += xr.w*p3.x - xi.w*p3.y;  a0i += xr.w*p3.y + xi.w*p3.x;
    float2 s0 = ps1[j+0], s1 = ps1[j+1], s2 = ps1[j+2], s3 = ps1[j+3];
    a1r += xr.x*s0.x - xi.x*s0.y;  a1i += xr.x*s0.y + xi.x*s0.x;
    a1r += xr.y*s1.x - xi.y*s1.y;  a1i += xr.y*s1.y + xi.y*s1.x;
    a1r += xr.z*s2.x - xi.z*s2.y;  a1i += xr.z*s2.y + xi.z*s2.x;
    a1r += xr.w*s3.x - xi.w*s3.y;  a1i += xr.w*s3.y + xi.w*s3.x;
  }
  size_t o0 = ((size_t)(b0    ) * HH + h) * DD + i;
  size_t o1 = ((size_t)(b0 + 1) * HH + h) * DD + i;
  qr[o0] = a0r; qi[o0] = a0i;
  qr[o1] = a1r; qi[o1] = a1i;
}

// ---------------------------------------------------------------------------
// K2: inv_nrm[m] = 1/sqrt(max(sum_d ur^2+ui^2, EPS)); fac[m] = sigmoid(s_logit)*inv^2
// one wave per row m.
// ---------------------------------------------------------------------------
__global__ __launch_bounds__(256) void k_norm(
    const float* __restrict__ u_r, const float* __restrict__ u_i,
    const float* __restrict__ s_logit, float* __restrict__ inv_nrm,
    float* __restrict__ fac) {
  int m = blockIdx.x * 4 + (threadIdx.x >> 6);
  int lane = threadIdx.x & 63;
  const float4* a = (const float4*)(u_r + (size_t)m * DD);
  const float4* b = (const float4*)(u_i + (size_t)m * DD);
  float4 x = a[lane], y = b[lane];
  float s = x.x*x.x + x.y*x.y + x.z*x.z + x.w*x.w
          + y.x*y.x + y.y*y.y + y.z*y.z + y.w*y.w;
  for (int off = 32; off; off >>= 1) s += __shfl_down(s, off);
  if (lane == 0) {
    float inv = 1.0f / sqrtf(fmaxf(s, 1e-8f));
    inv_nrm[m] = inv;
    float sig = 1.0f / (1.0f + expf(-s_logit[m]));
    fac[m] = sig * inv * inv;
  }
}

// ---------------------------------------------------------------------------
// K3: scores[bh,m] = fac[m] * ((ur.qr+ui.qi)^2 + (ur.qi-ui.qr)^2)   (u raw)
// 64x64 tile per block, 256 threads, 4x4 complex accumulators each.
// LDS tiles stored K-major so inner reads are conflict-free (strided-16 map).
// ---------------------------------------------------------------------------
__global__ __launch_bounds__(256) void k_scores(
    const float* __restrict__ qr, const float* __restrict__ qi,
    const float* __restrict__ u_r, const float* __restrict__ u_i,
    const float* __restrict__ fac, float* __restrict__ scores) {
  __shared__ float2 qt[32][64];
  __shared__ float2 ut[32][64];
  int m0  = blockIdx.x * 64;
  int bh0 = blockIdx.y * 64;
  int tid = threadIdx.x;
  int tx = tid & 15, ty = tid >> 4;
  int lrow = tid >> 3, lc4 = tid & 7;
  float accr[4][4] = {{0.f}}, acci[4][4] = {{0.f}};
  for (int k0 = 0; k0 < DD; k0 += 32) {
    __syncthreads();
#pragma unroll
    for (int half = 0; half < 2; ++half) {
      int row = lrow + 32 * half;
      float4 xr = *(const float4*)(qr + (size_t)(bh0 + row) * DD + k0 + lc4 * 4);
      float4 xi = *(const float4*)(qi + (size_t)(bh0 + row) * DD + k0 + lc4 * 4);
      qt[lc4*4+0][row] = make_float2(xr.x, xi.x);
      qt[lc4*4+1][row] = make_float2(xr.y, xi.y);
      qt[lc4*4+2][row] = make_float2(xr.z, xi.z);
      qt[lc4*4+3][row] = make_float2(xr.w, xi.w);
      float4 yr = *(const float4*)(u_r + (size_t)(m0 + row) * DD + k0 + lc4 * 4);
      float4 yi = *(const float4*)(u_i + (size_t)(m0 + row) * DD + k0 + lc4 * 4);
      ut[lc4*4+0][row] = make_float2(yr.x, yi.x);
      ut[lc4*4+1][row] = make_float2(yr.y, yi.y);
      ut[lc4*4+2][row] = make_float2(yr.z, yi.z);
      ut[lc4*4+3][row] = make_float2(yr.w, yi.w);
    }
    __syncthreads();
#pragma unroll 4
    for (int kk = 0; kk < 32; ++kk) {
      float2 qv[4], uv[4];
#pragma unroll
      for (int r = 0; r < 4; ++r) qv[r] = qt[kk][ty + 16*r];
#pragma unroll
      for (int c = 0; c < 4; ++c) uv[c] = ut[kk][tx + 16*c];
#pragma unroll
      for (int r = 0; r < 4; ++r)
#pragma unroll
        for (int c = 0; c < 4; ++c) {
          accr[r][c] += qv[r].x*uv[c].x + qv[r].y*uv[c].y;
          acci[r][c] += qv[r].y*uv[c].x - qv[r].x*uv[c].y;
        }
    }
  }
#pragma unroll
  for (int c = 0; c < 4; ++c) {
    int m = m0 + tx + 16*c;
    float f = fac[m];
#pragma unroll
    for (int r = 0; r < 4; ++r) {
      int bh = bh0 + ty + 16*r;
      scores[(size_t)bh * MM + m] = f * (accr[r][c]*accr[r][c] + acci[r][c]*acci[r][c]);
    }
  }
}

// ---------------------------------------------------------------------------
// K4: top-16 per row by 16 rounds of block-wide argmax (u64 packed key:
// [score bits | 8191-idx]); ties -> lower index, matching lax.top_k.
// ---------------------------------------------------------------------------
__global__ __launch_bounds__(256) void k_topk(
    const float* __restrict__ scores, float* __restrict__ topv, int* __restrict__ topi) {
  __shared__ float sv[MM];
  __shared__ unsigned long long redU[4];
  int bh = blockIdx.x, tid = threadIdx.x;
  const float* row = scores + (size_t)bh * MM;
  for (int i = tid; i < MM; i += 256) sv[i] = row[i];
  __syncthreads();
  for (int t = 0; t < 16; ++t) {
    unsigned long long best = 0ull;
    for (int i = tid; i < MM; i += 256) {
      float v = sv[i];
      if (v >= 0.f) {
        unsigned long long key = ((unsigned long long)__float_as_uint(v) << 32)
                                 | (unsigned)(MM - 1 - i);
        if (key > best) best = key;
      }
    }
    for (int off = 32; off; off >>= 1) {
      unsigned long long o = __shfl_down(best, off);
      if (o > best) best = o;
    }
    int lane = tid & 63, w = tid >> 6;
    if (lane == 0) redU[w] = best;
    __syncthreads();
    if (tid == 0) {
      best = redU[0];
      for (int s = 1; s < 4; ++s) if (redU[s] > best) best = redU[s];
      int idx = MM - 1 - (int)(best & 0xffffffffull);
      topv[bh*16 + t] = __uint_as_float((unsigned)(best >> 32));
      topi[bh*16 + t] = idx;
      sv[idx] = -1.f;   // excluded from future rounds (v >= 0 guard)
    }
    __syncthreads();
  }
}

// ---------------------------------------------------------------------------
// K5a: complex Householder factorization (LAPACK clarfg convention: beta real,
// sign = -sign(Re alpha)) of the 256x16 weighted-u matrix. One block per (b,h),
// thread d = row. Writes reflectors vT[bh][j][d] (v[j]=1 stored) and taus.
// ---------------------------------------------------------------------------
__global__ __launch_bounds__(256) void k_qr_fact(
    const float* __restrict__ u_r, const float* __restrict__ u_i,
    const float* __restrict__ inv_nrm,
    const float* __restrict__ topv, const int* __restrict__ topi,
    float2* __restrict__ vT, float2* __restrict__ tau_ws) {
  __shared__ float Ar[DD][17];
  __shared__ float Ai[DD][17];
  __shared__ float pwR[16][16], pwI[16][16];
  __shared__ float wvR[16], wvI[16];
  __shared__ float redS[4];
  __shared__ int   idxs[16];
  __shared__ float fA[16];
  __shared__ float tauSh[16][2];

  int bh = blockIdx.x;
  int tid = threadIdx.x;
  int d = tid;
  if (tid < 16) {
    int id = topi[bh*16 + tid];
    idxs[tid] = id;
    float w = sqrtf(fmaxf(topv[bh*16 + tid], 0.f));
    fA[tid] = w * inv_nrm[id];
  }
  __syncthreads();
  for (int j = 0; j < 16; ++j) {
    float f = fA[j];
    size_t base = (size_t)idxs[j] * DD + d;
    Ar[d][j] = u_r[base] * f;
    Ai[d][j] = u_i[base] * f;
  }
  __syncthreads();

  for (int j = 0; j < 16; ++j) {
    float ar = Ar[d][j], ai = Ai[d][j];
    float xn2 = (d > j) ? (ar*ar + ai*ai) : 0.f;
    for (int off = 32; off; off >>= 1) xn2 += __shfl_down(xn2, off);
    int lane = tid & 63, wv_ = tid >> 6;
    if (lane == 0) redS[wv_] = xn2;
    __syncthreads();
    xn2 = redS[0] + redS[1] + redS[2] + redS[3];
    float alr = Ar[j][j], ali = Ai[j][j];
    float taur, taui, scr, sci;
    if (xn2 == 0.f && ali == 0.f) {
      taur = 0.f; taui = 0.f; scr = 0.f; sci = 0.f;
    } else {
      float nrm  = sqrtf(alr*alr + ali*ali + xn2);
      float beta = (alr >= 0.f) ? -nrm : nrm;
      taur = (beta - alr) / beta;
      taui = -ali / beta;
      float dr = alr - beta, di = ali;
      float den = dr*dr + di*di;
      scr = dr / den; sci = -di / den;     // 1/(alpha-beta)
    }
    __syncthreads();   // everyone has read alpha before we overwrite col j
    if (d > j) {
      float vr = ar*scr - ai*sci;
      float vi = ar*sci + ai*scr;
      Ar[d][j] = vr; Ai[d][j] = vi;
    } else if (d == j) {
      Ar[d][j] = 1.f; Ai[d][j] = 0.f;
      tauSh[j][0] = taur; tauSh[j][1] = taui;
    }
    __syncthreads();
    // w_c = sum_{dd>=j} conj(v_dd) * A[dd][c]   for c > j   (16x16 layout)
    int c16 = tid & 15, seg = tid >> 4;
    float wr = 0.f, wi = 0.f;
    if (c16 > j) {
      for (int i2 = 0; i2 < 16; ++i2) {
        int dd = seg*16 + i2;
        if (dd >= j) {
          float vr = Ar[dd][j], vi = Ai[dd][j];
          float br = Ar[dd][c16], bi = Ai[dd][c16];
          wr += vr*br + vi*bi;
          wi += vr*bi - vi*br;
        }
      }
    }
    pwR[seg][c16] = wr; pwI[seg][c16] = wi;
    __syncthreads();
    if (tid < 16) {
      float swr = 0.f, swi = 0.f;
      for (int s = 0; s < 16; ++s) { swr += pwR[s][tid]; swi += pwI[s][tid]; }
      wvR[tid] = swr; wvI[tid] = swi;
    }
    __syncthreads();
    // A[:,c] -= conj(tau) * v * w_c   (zgeqrf applies H^H)
    if (d >= j) {
      float vr = Ar[d][j], vi = Ai[d][j];
      float tr = taur*vr + taui*vi;
      float ti = taur*vi - taui*vr;
      for (int cc = j+1; cc < 16; ++cc) {
        float wr2 = wvR[cc], wi2 = wvI[cc];
        Ar[d][cc] -= tr*wr2 - ti*wi2;
        Ai[d][cc] -= tr*wi2 + ti*wr2;
      }
    }
    __syncthreads();
  }
  for (int j = 0; j < 16; ++j)
    vT[((size_t)bh*16 + j) * DD + d] = make_float2(Ar[d][j], Ai[d][j]);
  if (tid < 16)
    tau_ws[bh*16 + tid] = make_float2(tauSh[tid][0], tauSh[tid][1]);
}

// ---------------------------------------------------------------------------
// K5b: Q = H_0...H_15 * I(:, :16) (zung2r backward accumulation), then
// diag[r] = sum_d conj(Q[d,r]) * w_mat[d,r], V = Q*diag, write U_re/V_re.
// ---------------------------------------------------------------------------
__global__ __launch_bounds__(256) void k_qr_form(
    const float2* __restrict__ vT, const float2* __restrict__ tau_ws,
    const float* __restrict__ w_r, const float* __restrict__ w_i,
    const float* __restrict__ topv, const int* __restrict__ topi,
    float* __restrict__ out) {
  __shared__ float Qr[DD][17], Qi[DD][17];
  __shared__ float vRs[DD], vIs[DD];
  __shared__ float pwR[16][16], pwI[16][16];
  __shared__ float wvR[16], wvI[16];
  __shared__ int   idxs[16];
  __shared__ float fW[16];
  __shared__ float dgR[16], dgI[16];

  int bh = blockIdx.x;
  int tid = threadIdx.x, d = tid;
  if (tid < 16) {
    idxs[tid] = topi[bh*16 + tid];
    fW[tid] = sqrtf(fmaxf(topv[bh*16 + tid], 0.f));
  }
#pragma unroll
  for (int c = 0; c < 16; ++c) { Qr[d][c] = (d == c) ? 1.f : 0.f; Qi[d][c] = 0.f; }
  __syncthreads();
  for (int j = 15; j >= 0; --j) {
    float2 v2 = vT[((size_t)bh*16 + j) * DD + d];
    vRs[d] = v2.x; vIs[d] = v2.y;
    float2 tau = tau_ws[bh*16 + j];
    __syncthreads();
    int c16 = tid & 15, seg = tid >> 4;
    float wr = 0.f, wi = 0.f;
    if (c16 >= j) {
      for (int i2 = 0; i2 < 16; ++i2) {
        int dd = seg*16 + i2;
        if (dd >= j) {
          float vr = vRs[dd], vi = vIs[dd];
          float br = Qr[dd][c16], bi = Qi[dd][c16];
          wr += vr*br + vi*bi;
          wi += vr*bi - vi*br;
        }
      }
    }
    pwR[seg][c16] = wr; pwI[seg][c16] = wi;
    __syncthreads();
    if (tid < 16) {
      float swr = 0.f, swi = 0.f;
      for (int s = 0; s < 16; ++s) { swr += pwR[s][tid]; swi += pwI[s][tid]; }
      wvR[tid] = swr; wvI[tid] = swi;
    }
    __syncthreads();
    if (d >= j) {
      float vr = vRs[d], vi = vIs[d];
      float tr = tau.x*vr - tau.y*vi;   // tau * v (zung2r applies H)
      float ti = tau.x*vi + tau.y*vr;
      for (int cc = j; cc < 16; ++cc) {
        Qr[d][cc] -= tr*wvR[cc] - ti*wvI[cc];
        Qi[d][cc] -= tr*wvI[cc] + ti*wvR[cc];
      }
    }
    __syncthreads();
  }
  // diag[r] = sum_d conj(Q[d,r]) * (w_row[idx_r] * weight_r)[d]
  {
    int r16 = tid & 15, seg = tid >> 4;
    float fr = fW[r16];
    size_t rowb = (size_t)idxs[r16] * DD + seg*16;
    float sr = 0.f, si = 0.f;
    for (int i2 = 0; i2 < 16; ++i2) {
      int dd = seg*16 + i2;
      float wr2 = w_r[rowb + i2] * fr;
      float wi2 = w_i[rowb + i2] * fr;
      float qr2 = Qr[dd][r16], qi2 = Qi[dd][r16];
      sr += qr2*wr2 + qi2*wi2;
      si += qr2*wi2 - qi2*wr2;
    }
    pwR[seg][r16] = sr; pwI[seg][r16] = si;
  }
  __syncthreads();
  if (tid < 16) {
    float sr = 0.f, si = 0.f;
    for (int s = 0; s < 16; ++s) { sr += pwR[s][tid]; si += pwI[s][tid]; }
    dgR[tid] = sr; dgI[tid] = si;
  }
  __syncthreads();
  size_t baseU = ((size_t)bh * DD + d) * 32;
  size_t baseV = (size_t)BH * DD * 32 + baseU;
  float4* oU = (float4*)(out + baseU);
  float4* oV = (float4*)(out + baseV);
#pragma unroll
  for (int r = 0; r < 16; r += 2) {
    float q0r = Qr[d][r],   q0i = Qi[d][r];
    float q1r = Qr[d][r+1], q1i = Qi[d][r+1];
    oU[r >> 1] = make_float4(q0r, q0i, q1r, q1i);
    float v0r = q0r*dgR[r]   - q0i*dgI[r];
    float v0i = q0r*dgI[r]   + q0i*dgR[r];
    float v1r = q1r*dgR[r+1] - q1i*dgI[r+1];
    float v1i = q1r*dgI[r+1] + q1i*dgR[r+1];
    oV[r >> 1] = make_float4(v0r, v0i, v1r, v1i);
  }
}

// ---------------------------------------------------------------------------
extern "C" void kernel_launch(void* const* d_in, const int* in_sizes, int n_in,
                              void* d_out, int out_size, void* d_ws, size_t ws_size,
                              hipStream_t stream) {
  (void)in_sizes; (void)n_in; (void)out_size; (void)ws_size;
  const float* psi     = (const float*)d_in[0];
  const float* u_r     = (const float*)d_in[1];
  const float* u_i     = (const float*)d_in[2];
  const float* w_r     = (const float*)d_in[3];
  const float* w_i     = (const float*)d_in[4];
  const float* s_logit = (const float*)d_in[5];
  const float* probe_r = (const float*)d_in[6];
  const float* probe_i = (const float*)d_in[7];
  // d_in[8]=k(=32), d_in[9]=rank(=16): fixed by problem shape, only top-16 matters.

  float* ws      = (float*)d_ws;
  float* qr      = ws;                 // 1024*256
  float* qi      = ws + 262144;        // 1024*256
  float* inv_nrm = ws + 524288;        // 8192
  float* fac     = ws + 532480;        // 8192
  float* scores  = ws + 540672;        // 1024*8192 (reused as vT float2 after topk)
  float* topv    = ws + 8929280;       // 1024*16
  int*   topi    = (int*)(ws + 8945664); // 1024*16
  float2* tau_ws = (float2*)(ws + 8962048); // 1024*16 float2
  float* out     = (float*)d_out;

  hipLaunchKernelGGL(k_q,       dim3(BB/2, HH), dim3(256), 0, stream,
                     psi, probe_r, probe_i, qr, qi);
  hipLaunchKernelGGL(k_norm,    dim3(MM/4),     dim3(256), 0, stream,
                     u_r, u_i, s_logit, inv_nrm, fac);
  hipLaunchKernelGGL(k_scores,  dim3(MM/64, BH/64), dim3(256), 0, stream,
                     qr, qi, u_r, u_i, fac, scores);
  hipLaunchKernelGGL(k_topk,    dim3(BH),       dim3(256), 0, stream,
                     scores, topv, topi);
  hipLaunchKernelGGL(k_qr_fact, dim3(BH),       dim3(256), 0, stream,
                     u_r, u_i, inv_nrm, topv, topi, (float2*)scores, tau_ws);
  hipLaunchKernelGGL(k_qr_form, dim3(BH),       dim3(256), 0, stream,
                     (const float2*)scores, tau_ws, w_r, w_i, topv, topi, out);
}

// Round 2
// 576.796 us; speedup vs baseline: 1.0696x; 1.0696x over previous
//
#include <hip/hip_runtime.h>
#include <math.h>

// Problem constants (fixed by setup_inputs)
#define BB 128
#define HH 8
#define DD 256
#define MM 8192
#define BH (BB*HH)   // 1024
#define RANK 16

// ---------------------------------------------------------------------------
// K1: q[b,h,i] = sum_j (probe_r[h,i,j] + i probe_i[h,i,j]) * (pr[b,j] + i pi[b,j])
// ---------------------------------------------------------------------------
__global__ __launch_bounds__(256) void k_q(
    const float* __restrict__ psi, const float* __restrict__ probe_r,
    const float* __restrict__ probe_i, float* __restrict__ qr, float* __restrict__ qi) {
  __shared__ float2 ps0[DD];
  __shared__ float2 ps1[DD];
  int b0 = blockIdx.x * 2;
  int h  = blockIdx.y;
  int i  = threadIdx.x;
  ps0[i] = ((const float2*)psi)[(size_t)b0 * DD + i];
  ps1[i] = ((const float2*)psi)[(size_t)(b0 + 1) * DD + i];
  __syncthreads();
  const float* rr = probe_r + ((size_t)h * DD + i) * DD;
  const float* ri = probe_i + ((size_t)h * DD + i) * DD;
  float a0r = 0.f, a0i = 0.f, a1r = 0.f, a1i = 0.f;
  for (int j = 0; j < DD; j += 4) {
    float4 xr = *(const float4*)(rr + j);
    float4 xi = *(const float4*)(ri + j);
    float2 p0 = ps0[j+0], p1 = ps0[j+1], p2 = ps0[j+2], p3 = ps0[j+3];
    a0r += xr.x*p0.x - xi.x*p0.y;  a0i += xr.x*p0.y + xi.x*p0.x;
    a0r += xr.y*p1.x - xi.y*p1.y;  a0i += xr.y*p1.y + xi.y*p1.x;
    a0r += xr.z*p2.x - xi.z*p2.y;  a0i += xr.z*p2.y + xi.z*p2.x;
    a0r += xr.w*p3.x - xi.w*p3.y;  a0i += xr.w*p3.y + xi.w*p3.x;
    float2 s0 = ps1[j+0], s1 = ps1[j+1], s2 = ps1[j+2], s3 = ps1[j+3];
    a1r += xr.x*s0.x - xi.x*s0.y;  a1i += xr.x*s0.y + xi.x*s0.x;
    a1r += xr.y*s1.x - xi.y*s1.y;  a1i += xr.y*s1.y + xi.y*s1.x;
    a1r += xr.z*s2.x - xi.z*s2.y;  a1i += xr.z*s2.y + xi.z*s2.x;
    a1r += xr.w*s3.x - xi.w*s3.y;  a1i += xr.w*s3.y + xi.w*s3.x;
  }
  size_t o0 = ((size_t)(b0    ) * HH + h) * DD + i;
  size_t o1 = ((size_t)(b0 + 1) * HH + h) * DD + i;
  qr[o0] = a0r; qi[o0] = a0i;
  qr[o1] = a1r; qi[o1] = a1i;
}

// ---------------------------------------------------------------------------
// K2: inv_nrm / fac per row m
// ---------------------------------------------------------------------------
__global__ __launch_bounds__(256) void k_norm(
    const float* __restrict__ u_r, const float* __restrict__ u_i,
    const float* __restrict__ s_logit, float* __restrict__ inv_nrm,
    float* __restrict__ fac) {
  int m = blockIdx.x * 4 + (threadIdx.x >> 6);
  int lane = threadIdx.x & 63;
  const float4* a = (const float4*)(u_r + (size_t)m * DD);
  const float4* b = (const float4*)(u_i + (size_t)m * DD);
  float4 x = a[lane], y = b[lane];
  float s = x.x*x.x + x.y*x.y + x.z*x.z + x.w*x.w
          + y.x*y.x + y.y*y.y + y.z*y.z + y.w*y.w;
  for (int off = 32; off; off >>= 1) s += __shfl_down(s, off);
  if (lane == 0) {
    float inv = 1.0f / sqrtf(fmaxf(s, 1e-8f));
    inv_nrm[m] = inv;
    float sig = 1.0f / (1.0f + expf(-s_logit[m]));
    fac[m] = sig * inv * inv;
  }
}

// ---------------------------------------------------------------------------
// K3: scores[bh,m].  Block tile 128(bh) x 64(m), K-tile 32, 8x4 complex acc
// per thread.  LDS rows padded (+1 float2) -> staging-write bank stride 2
// (2-way max, free).
// ---------------------------------------------------------------------------
__global__ __launch_bounds__(256) void k_scores(
    const float* __restrict__ qr, const float* __restrict__ qi,
    const float* __restrict__ u_r, const float* __restrict__ u_i,
    const float* __restrict__ fac, float* __restrict__ scores) {
  __shared__ float2 qt[32][129];   // [kk][bh_row], padded
  __shared__ float2 ut[32][65];    // [kk][m_row],  padded
  int m0  = blockIdx.x * 64;
  int bh0 = blockIdx.y * 128;
  int tid = threadIdx.x;
  int tx = tid & 15, ty = tid >> 4;          // compute map
  int qrow = tid >> 1, qk = (tid & 1) * 16;  // q staging map (128 rows x 32 k)
  int urow = tid >> 2, uk = (tid & 3) * 8;   // u staging map (64 rows x 32 k)
  float accr[8][4] = {{0.f}}, acci[8][4] = {{0.f}};
  for (int k0 = 0; k0 < DD; k0 += 32) {
    __syncthreads();
    {
      const float4* pr = (const float4*)(qr + (size_t)(bh0 + qrow) * DD + k0 + qk);
      const float4* pi = (const float4*)(qi + (size_t)(bh0 + qrow) * DD + k0 + qk);
      float rb[16], ib[16];
      *(float4*)&rb[0]  = pr[0]; *(float4*)&rb[4]  = pr[1];
      *(float4*)&rb[8]  = pr[2]; *(float4*)&rb[12] = pr[3];
      *(float4*)&ib[0]  = pi[0]; *(float4*)&ib[4]  = pi[1];
      *(float4*)&ib[8]  = pi[2]; *(float4*)&ib[12] = pi[3];
#pragma unroll
      for (int e = 0; e < 16; ++e) qt[qk + e][qrow] = make_float2(rb[e], ib[e]);
      const float4* sr = (const float4*)(u_r + (size_t)(m0 + urow) * DD + k0 + uk);
      const float4* si = (const float4*)(u_i + (size_t)(m0 + urow) * DD + k0 + uk);
      float rc[8], ic[8];
      *(float4*)&rc[0] = sr[0]; *(float4*)&rc[4] = sr[1];
      *(float4*)&ic[0] = si[0]; *(float4*)&ic[4] = si[1];
#pragma unroll
      for (int e = 0; e < 8; ++e) ut[uk + e][urow] = make_float2(rc[e], ic[e]);
    }
    __syncthreads();
#pragma unroll 2
    for (int kk = 0; kk < 32; ++kk) {
      float2 qv[8], uv[4];
#pragma unroll
      for (int r = 0; r < 8; ++r) qv[r] = qt[kk][ty + 16*r];
#pragma unroll
      for (int c = 0; c < 4; ++c) uv[c] = ut[kk][tx + 16*c];
#pragma unroll
      for (int r = 0; r < 8; ++r)
#pragma unroll
        for (int c = 0; c < 4; ++c) {
          accr[r][c] += qv[r].x*uv[c].x + qv[r].y*uv[c].y;
          acci[r][c] += qv[r].y*uv[c].x - qv[r].x*uv[c].y;
        }
    }
  }
#pragma unroll
  for (int c = 0; c < 4; ++c) {
    int m = m0 + tx + 16*c;
    float f = fac[m];
#pragma unroll
    for (int r = 0; r < 8; ++r) {
      int bh = bh0 + ty + 16*r;
      scores[(size_t)bh * MM + m] = f * (accr[r][c]*accr[r][c] + acci[r][c]*acci[r][c]);
    }
  }
}

// ---------------------------------------------------------------------------
// K4: top-16 per row, 16 rounds of block argmax; ties -> lower index.
// ---------------------------------------------------------------------------
__global__ __launch_bounds__(256) void k_topk(
    const float* __restrict__ scores, float* __restrict__ topv, int* __restrict__ topi) {
  __shared__ float sv[MM];
  __shared__ unsigned long long redU[4];
  int bh = blockIdx.x, tid = threadIdx.x;
  const float* row = scores + (size_t)bh * MM;
  for (int i = tid; i < MM; i += 256) sv[i] = row[i];
  __syncthreads();
  for (int t = 0; t < 16; ++t) {
    unsigned long long best = 0ull;
    for (int i = tid; i < MM; i += 256) {
      float v = sv[i];
      if (v >= 0.f) {
        unsigned long long key = ((unsigned long long)__float_as_uint(v) << 32)
                                 | (unsigned)(MM - 1 - i);
        if (key > best) best = key;
      }
    }
    for (int off = 32; off; off >>= 1) {
      unsigned long long o = __shfl_down(best, off);
      if (o > best) best = o;
    }
    int lane = tid & 63, w = tid >> 6;
    if (lane == 0) redU[w] = best;
    __syncthreads();
    if (tid == 0) {
      best = redU[0];
      for (int s = 1; s < 4; ++s) if (redU[s] > best) best = redU[s];
      int idx = MM - 1 - (int)(best & 0xffffffffull);
      topv[bh*16 + t] = __uint_as_float((unsigned)(best >> 32));
      topi[bh*16 + t] = idx;
      sv[idx] = -1.f;
    }
    __syncthreads();
  }
}

// ---------------------------------------------------------------------------
// K5 (merged): Householder factorization (LAPACK clarfg convention) of the
// 256x16 weighted-u matrix, then IN-PLACE zung2r backward Q accumulation,
// then diag(coeff), V = Q*diag, and output writes.  One block per (b,h).
// ---------------------------------------------------------------------------
__global__ __launch_bounds__(256) void k_qr(
    const float* __restrict__ u_r, const float* __restrict__ u_i,
    const float* __restrict__ inv_nrm,
    const float* __restrict__ w_r, const float* __restrict__ w_i,
    const float* __restrict__ topv, const int* __restrict__ topi,
    float* __restrict__ out) {
  __shared__ float Ar[DD][17];
  __shared__ float Ai[DD][17];
  __shared__ float pwR[16][16], pwI[16][16];
  __shared__ float wvR[16], wvI[16];
  __shared__ float redS[4];
  __shared__ int   idxs[16];
  __shared__ float fA[16], fW[16];
  __shared__ float tauR[16], tauI[16];
  __shared__ float dgR[16], dgI[16];

  int bh = blockIdx.x;
  int tid = threadIdx.x;
  int d = tid;
  if (tid < 16) {
    int id = topi[bh*16 + tid];
    idxs[tid] = id;
    float w = sqrtf(fmaxf(topv[bh*16 + tid], 0.f));
    fW[tid] = w;
    fA[tid] = w * inv_nrm[id];
  }
  __syncthreads();
  for (int j = 0; j < 16; ++j) {
    float f = fA[j];
    size_t base = (size_t)idxs[j] * DD + d;
    Ar[d][j] = u_r[base] * f;
    Ai[d][j] = u_i[base] * f;
  }
  __syncthreads();

  // ---- Phase A: factorize (clarfg convention: beta real, sign=-sign(Re a)) ----
  for (int j = 0; j < 16; ++j) {
    float ar = Ar[d][j], ai = Ai[d][j];
    float xn2 = (d > j) ? (ar*ar + ai*ai) : 0.f;
    for (int off = 32; off; off >>= 1) xn2 += __shfl_down(xn2, off);
    int lane = tid & 63, wv_ = tid >> 6;
    if (lane == 0) redS[wv_] = xn2;
    __syncthreads();
    xn2 = redS[0] + redS[1] + redS[2] + redS[3];
    float alr = Ar[j][j], ali = Ai[j][j];
    float taur, taui, scr, sci;
    if (xn2 == 0.f && ali == 0.f) {
      taur = 0.f; taui = 0.f; scr = 0.f; sci = 0.f;
    } else {
      float nrm  = sqrtf(alr*alr + ali*ali + xn2);
      float beta = (alr >= 0.f) ? -nrm : nrm;
      taur = (beta - alr) / beta;
      taui = -ali / beta;
      float dr = alr - beta, di = ali;
      float den = dr*dr + di*di;
      scr = dr / den; sci = -di / den;     // 1/(alpha-beta)
    }
    __syncthreads();   // all reads of alpha done before col-j overwrite
    if (d > j) {
      float vr = ar*scr - ai*sci;
      float vi = ar*sci + ai*scr;
      Ar[d][j] = vr; Ai[d][j] = vi;
    } else if (d == j) {
      Ar[d][j] = 1.f; Ai[d][j] = 0.f;
      tauR[j] = taur; tauI[j] = taui;
    }
    __syncthreads();
    // w_c = sum_{dd>=j} conj(v_dd) * A[dd][c]  for c > j
    int c16 = tid & 15, seg = tid >> 4;
    float wr = 0.f, wi = 0.f;
    if (c16 > j) {
      for (int i2 = 0; i2 < 16; ++i2) {
        int dd = seg*16 + i2;
        if (dd >= j) {
          float vr = Ar[dd][j], vi = Ai[dd][j];
          float br = Ar[dd][c16], bi = Ai[dd][c16];
          wr += vr*br + vi*bi;
          wi += vr*bi - vi*br;
        }
      }
    }
    pwR[seg][c16] = wr; pwI[seg][c16] = wi;
    __syncthreads();
    if (tid < 16) {
      float swr = 0.f, swi = 0.f;
      for (int s = 0; s < 16; ++s) { swr += pwR[s][tid]; swi += pwI[s][tid]; }
      wvR[tid] = swr; wvI[tid] = swi;
    }
    __syncthreads();
    // A[:,c] -= conj(tau) * v * w_c   (geqrf applies H^H)
    if (d >= j) {
      float vr = Ar[d][j], vi = Ai[d][j];
      float tr = taur*vr + taui*vi;
      float ti = taur*vi - taui*vr;
      for (int cc = j+1; cc < 16; ++cc) {
        float wr2 = wvR[cc], wi2 = wvI[cc];
        Ar[d][cc] -= tr*wr2 - ti*wi2;
        Ai[d][cc] -= tr*wi2 + ti*wr2;
      }
    }
    __syncthreads();
  }

  // ---- Phase B: zung2r in place (Q overwrites A) ----
  for (int i = 15; i >= 0; --i) {
    float tr = tauR[i], ti = tauI[i];
    int c16 = tid & 15, seg = tid >> 4;
    float wr = 0.f, wi = 0.f;
    if (c16 > i) {
      for (int i2 = 0; i2 < 16; ++i2) {
        int dd = seg*16 + i2;
        if (dd >= i) {
          float vr = Ar[dd][i], vi = Ai[dd][i];
          float br = Ar[dd][c16], bi = Ai[dd][c16];
          wr += vr*br + vi*bi;
          wi += vr*bi - vi*br;
        }
      }
    }
    pwR[seg][c16] = wr; pwI[seg][c16] = wi;
    __syncthreads();
    if (tid < 16) {
      float swr = 0.f, swi = 0.f;
      for (int s = 0; s < 16; ++s) { swr += pwR[s][tid]; swi += pwI[s][tid]; }
      wvR[tid] = swr; wvI[tid] = swi;
    }
    __syncthreads();
    float vr = Ar[d][i], vi = Ai[d][i];   // own row of v, read before overwrite
    if (d >= i) {
      float tvr = tr*vr - ti*vi;          // tau * v (zung2r applies H)
      float tvi = tr*vi + ti*vr;
      for (int cc = i+1; cc < 16; ++cc) {
        Ar[d][cc] -= tvr*wvR[cc] - tvi*wvI[cc];
        Ai[d][cc] -= tvr*wvI[cc] + tvi*wvR[cc];
      }
      // column i of Q: e_i - tau*v
      if (d > i) {
        Ar[d][i] = -(tr*vr - ti*vi);
        Ai[d][i] = -(tr*vi + ti*vr);
      } else {            // d == i
        Ar[d][i] = 1.f - tr;
        Ai[d][i] = -ti;
      }
    } else {
      Ar[d][i] = 0.f;
      Ai[d][i] = 0.f;
    }
    __syncthreads();
  }

  // ---- diag[r] = sum_d conj(Q[d,r]) * (w_row[idx_r] * weight_r)[d] ----
  {
    int r16 = tid & 15, seg = tid >> 4;
    float fr = fW[r16];
    size_t rowb = (size_t)idxs[r16] * DD + seg*16;
    float sr = 0.f, si = 0.f;
    for (int i2 = 0; i2 < 16; ++i2) {
      int dd = seg*16 + i2;
      float wr2 = w_r[rowb + i2] * fr;
      float wi2 = w_i[rowb + i2] * fr;
      float qr2 = Ar[dd][r16], qi2 = Ai[dd][r16];
      sr += qr2*wr2 + qi2*wi2;
      si += qr2*wi2 - qi2*wr2;
    }
    pwR[seg][r16] = sr; pwI[seg][r16] = si;
  }
  __syncthreads();
  if (tid < 16) {
    float sr = 0.f, si = 0.f;
    for (int s = 0; s < 16; ++s) { sr += pwR[s][tid]; si += pwI[s][tid]; }
    dgR[tid] = sr; dgI[tid] = si;
  }
  __syncthreads();
  size_t baseU = ((size_t)bh * DD + d) * 32;
  size_t baseV = (size_t)BH * DD * 32 + baseU;
  float4* oU = (float4*)(out + baseU);
  float4* oV = (float4*)(out + baseV);
#pragma unroll
  for (int r = 0; r < 16; r += 2) {
    float q0r = Ar[d][r],   q0i = Ai[d][r];
    float q1r = Ar[d][r+1], q1i = Ai[d][r+1];
    oU[r >> 1] = make_float4(q0r, q0i, q1r, q1i);
    float v0r = q0r*dgR[r]   - q0i*dgI[r];
    float v0i = q0r*dgI[r]   + q0i*dgR[r];
    float v1r = q1r*dgR[r+1] - q1i*dgI[r+1];
    float v1i = q1r*dgI[r+1] + q1i*dgR[r+1];
    oV[r >> 1] = make_float4(v0r, v0i, v1r, v1i);
  }
}

// ---------------------------------------------------------------------------
extern "C" void kernel_launch(void* const* d_in, const int* in_sizes, int n_in,
                              void* d_out, int out_size, void* d_ws, size_t ws_size,
                              hipStream_t stream) {
  (void)in_sizes; (void)n_in; (void)out_size; (void)ws_size;
  const float* psi     = (const float*)d_in[0];
  const float* u_r     = (const float*)d_in[1];
  const float* u_i     = (const float*)d_in[2];
  const float* w_r     = (const float*)d_in[3];
  const float* w_i     = (const float*)d_in[4];
  const float* s_logit = (const float*)d_in[5];
  const float* probe_r = (const float*)d_in[6];
  const float* probe_i = (const float*)d_in[7];
  // d_in[8]=k(=32), d_in[9]=rank(=16): fixed by problem shape; only top-16 matters.

  float* ws      = (float*)d_ws;
  float* qr      = ws;                 // 1024*256
  float* qi      = ws + 262144;        // 1024*256
  float* inv_nrm = ws + 524288;        // 8192
  float* fac     = ws + 532480;        // 8192
  float* scores  = ws + 540672;        // 1024*8192
  float* topv    = ws + 8929280;       // 1024*16
  int*   topi    = (int*)(ws + 8945664); // 1024*16
  float* out     = (float*)d_out;

  hipLaunchKernelGGL(k_q,      dim3(BB/2, HH),       dim3(256), 0, stream,
                     psi, probe_r, probe_i, qr, qi);
  hipLaunchKernelGGL(k_norm,   dim3(MM/4),           dim3(256), 0, stream,
                     u_r, u_i, s_logit, inv_nrm, fac);
  hipLaunchKernelGGL(k_scores, dim3(MM/64, BH/128),  dim3(256), 0, stream,
                     qr, qi, u_r, u_i, fac, scores);
  hipLaunchKernelGGL(k_topk,   dim3(BH),             dim3(256), 0, stream,
                     scores, topv, topi);
  hipLaunchKernelGGL(k_qr,     dim3(BH),             dim3(256), 0, stream,
                     u_r, u_i, inv_nrm, w_r, w_i, topv, topi, out);
}